// Round 1
// baseline (567.167 us; speedup 1.0000x reference)
//
#include <hip/hip_runtime.h>
#include <cstddef>

#define NB 4
#define NP 8192
#define NK 16
#define NC 128

using short8   = __attribute__((ext_vector_type(8))) short;
using ushort4v = __attribute__((ext_vector_type(4))) unsigned short;
using floatx4  = __attribute__((ext_vector_type(4))) float;

__device__ __forceinline__ unsigned short f2bf(float f) {
    union { float f; unsigned u; } v; v.f = f;
    unsigned r = v.u + 0x7FFFu + ((v.u >> 16) & 1u);   // RNE
    return (unsigned short)(r >> 16);
}

#define MFMA(a, b, c) __builtin_amdgcn_mfma_f32_16x16x32_bf16((a), (b), (c), 0, 0, 0)

// ---------------------------------------------------------------------------
// Weight packing: fp32 -> bf16, edge_W1 reordered to [feat(128)|rel(3)|pad->160]
// Regions (bf16 elems): offW1p 16384 | eW1p 3*128*160 | eW2p 3*16384 |
//                       uW1p 3*32768 | uW2p 3*16384      (total 274432)
// ---------------------------------------------------------------------------
__global__ void pack_weights_k(const float* __restrict__ offW1,
                               const float* __restrict__ eW1,
                               const float* __restrict__ eW2,
                               const float* __restrict__ uW1,
                               const float* __restrict__ uW2,
                               unsigned short* __restrict__ offW1p,
                               unsigned short* __restrict__ eW1p,
                               unsigned short* __restrict__ eW2p,
                               unsigned short* __restrict__ uW1p,
                               unsigned short* __restrict__ uW2p)
{
    int i = blockIdx.x * 256 + threadIdx.x;
    if (i < 16384) { offW1p[i] = f2bf(offW1[i]); return; }
    i -= 16384;
    if (i < 61440) {
        int tt = i / 20480, rem = i % 20480;
        int j = rem / 160, k = rem % 160;
        float v = 0.f;
        if (k < 128)      v = eW1[(tt * 128 + j) * 131 + 3 + k];   // feat part
        else if (k < 131) v = eW1[(tt * 128 + j) * 131 + (k - 128)]; // rel part
        eW1p[i] = f2bf(v);
        return;
    }
    i -= 61440;
    if (i < 49152) { eW2p[i] = f2bf(eW2[i]); return; }
    i -= 49152;
    if (i < 98304) { uW1p[i] = f2bf(uW1[i]); return; }
    i -= 98304;
    if (i < 49152) { uW2p[i] = f2bf(uW2[i]); }
}

// ---------------------------------------------------------------------------
// Fused iteration kernel. Block = 256 thr (4 waves), handles P=8 points.
// Wave w owns output column-tiles {2w, 2w+1}; weight B-frags live in VGPRs.
// ---------------------------------------------------------------------------
__global__ __launch_bounds__(256, 2)
void stab_iter_k(const float* __restrict__ Fin, float* __restrict__ Fout,
                 const float* __restrict__ xyz, const int* __restrict__ knn,
                 const unsigned short* __restrict__ offW1p,
                 const float* __restrict__ offW2,
                 const float* __restrict__ offb1,
                 const float* __restrict__ offb2,
                 const unsigned short* __restrict__ eW1p,
                 const unsigned short* __restrict__ eW2p,
                 const float* __restrict__ eb1, const float* __restrict__ eb2,
                 const unsigned short* __restrict__ uW1p,
                 const unsigned short* __restrict__ uW2p,
                 const float* __restrict__ ub1, const float* __restrict__ ub2)
{
    // LDS: 40960 + 12544 + 4096 + 512 + 96 = 58208 B  (<= 64 KB, 2 blocks/CU)
    __shared__ __align__(16) unsigned short s_EI[128 * 160]; // edge inputs bf16
    __shared__ __align__(16) float          s_R1[3136];      // aliased region
    __shared__ __align__(16) float          s_FSELF[8 * NC]; // self feats fp32
    __shared__ int   s_KNN[128];
    __shared__ float s_CTR[8][3];

    unsigned short* OFF_A = (unsigned short*)s_R1;                 // 16x136 bf16
    float*          HOFF  = (float*)((char*)s_R1 + 4352);          // 16x128 f32
    float*          AGG   = s_R1;                                  // 8x128 f32
    unsigned short* UIN   = (unsigned short*)((char*)s_R1 + 4096); // 16x264 bf16
    unsigned short* H     = s_EI;                                  // 128x136 bf16 (alias)
    unsigned short* H2    = s_EI;                                  // 16x136 bf16 (alias)

    const int blk = blockIdx.x;
    const int b   = blk >> 10;           // 1024 blocks per batch
    const int n0  = (blk & 1023) << 3;   // 8 points per block
    const int t   = threadIdx.x;
    const int wv  = t >> 6;
    const int ln  = t & 63;
    const int q   = ln >> 4;
    const int r   = ln & 15;
    const int cg0 = wv << 1;             // first column-tile of this wave

    // ---- stage 1: load self features (fp32 + bf16) and knn indices
    {
        int row = t >> 5;
        int c4  = (t & 31) << 2;
        float4 f = *(const float4*)(Fin + (size_t)(b * NP + n0 + row) * NC + c4);
        *(float4*)&s_FSELF[row * NC + c4] = f;
        ushort4v u = { f2bf(f.x), f2bf(f.y), f2bf(f.z), f2bf(f.w) };
        *(ushort4v*)&OFF_A[row * 136 + c4] = u;
        if (t < 128)
            s_KNN[t] = knn[(size_t)(b * NP + n0 + (t >> 4)) * NK + (t & 15)];
    }
    __syncthreads();

    // ---- stage 2: offset MLP layer 1 (MFMA), h -> HOFF (fp32, relu'd)
    {
        short8 wf[2][4];
#pragma unroll
        for (int c = 0; c < 2; ++c) {
            int wrow = ((cg0 + c) * 16 + r) * NC;
#pragma unroll
            for (int ks = 0; ks < 4; ++ks)
                wf[c][ks] = *(const short8*)(offW1p + wrow + ks * 32 + q * 8);
        }
        short8 af[4];
#pragma unroll
        for (int ks = 0; ks < 4; ++ks)
            af[ks] = *(const short8*)&OFF_A[r * 136 + ks * 32 + q * 8];
        floatx4 acc[2] = { {0.f,0.f,0.f,0.f}, {0.f,0.f,0.f,0.f} };
#pragma unroll
        for (int c = 0; c < 2; ++c)
#pragma unroll
            for (int ks = 0; ks < 4; ++ks)
                acc[c] = MFMA(af[ks], wf[c][ks], acc[c]);
#pragma unroll
        for (int c = 0; c < 2; ++c) {
            int col = (cg0 + c) * 16 + r;
            float bv = offb1[col];
#pragma unroll
            for (int i = 0; i < 4; ++i)
                HOFF[(q * 4 + i) * NC + col] = fmaxf(acc[c][i] + bv, 0.f);
        }
    }
    __syncthreads();

    // ---- stage 3: delta_xyz (3x128 dot, fp32) -> center
    if (t < 24) {
        int p = t / 3, o = t % 3;
        float s = offb2[o];
        const float* w = offW2 + o * NC;
        const float* h = HOFF + p * NC;
#pragma unroll 4
        for (int j = 0; j < NC; ++j) s += w[j] * h[j];
        s_CTR[p][o] = xyz[(size_t)(b * NP + n0 + p) * 3 + o] + s;
    }
    __syncthreads();

    // ---- stage 4: assemble edge inputs [feat(128)|rel(3)|0(29)] in bf16
    {
        int rw = t >> 5;
        int c4 = (t & 31) << 2;
        for (int pass = 0; pass < 16; ++pass) {
            int row = pass * 8 + rw;
            int nb  = s_KNN[row];
            float4 f = *(const float4*)(Fin + (size_t)(b * NP + nb) * NC + c4);
            ushort4v u = { f2bf(f.x), f2bf(f.y), f2bf(f.z), f2bf(f.w) };
            *(ushort4v*)&s_EI[row * 160 + c4] = u;
        }
    }
    if (t < 128) {
        int row = t, p = t >> 4;
        int nb  = s_KNN[row];
        const float* xp = xyz + (size_t)(b * NP + nb) * 3;
        ushort4v rv = { f2bf(xp[0] - s_CTR[p][0]), f2bf(xp[1] - s_CTR[p][1]),
                        f2bf(xp[2] - s_CTR[p][2]), 0 };
        *(ushort4v*)&s_EI[row * 160 + 128] = rv;
        ushort4v z = {0, 0, 0, 0};
#pragma unroll
        for (int g = 1; g < 8; ++g)
            *(ushort4v*)&s_EI[row * 160 + 128 + g * 4] = z;
    }
    __syncthreads();

    // ---- stage 5: edge MLP layer 1, 128x160 @ 160->128
    floatx4 acc1[8][2];
    {
        short8 wf[2][5];
#pragma unroll
        for (int c = 0; c < 2; ++c) {
            int wrow = ((cg0 + c) * 16 + r) * 160;
#pragma unroll
            for (int ks = 0; ks < 5; ++ks)
                wf[c][ks] = *(const short8*)(eW1p + wrow + ks * 32 + q * 8);
        }
#pragma unroll
        for (int rt = 0; rt < 8; ++rt) {
            acc1[rt][0] = (floatx4){0.f,0.f,0.f,0.f};
            acc1[rt][1] = (floatx4){0.f,0.f,0.f,0.f};
            short8 af[5];
#pragma unroll
            for (int ks = 0; ks < 5; ++ks)
                af[ks] = *(const short8*)&s_EI[(rt * 16 + r) * 160 + ks * 32 + q * 8];
#pragma unroll
            for (int c = 0; c < 2; ++c)
#pragma unroll
                for (int ks = 0; ks < 5; ++ks)
                    acc1[rt][c] = MFMA(af[ks], wf[c][ks], acc1[rt][c]);
        }
    }
    __syncthreads();   // everyone done reading EI; H aliases it
    {
        float b0  = eb1[cg0 * 16 + r];
        float b1v = eb1[(cg0 + 1) * 16 + r];
#pragma unroll
        for (int rt = 0; rt < 8; ++rt)
#pragma unroll
            for (int c = 0; c < 2; ++c) {
                int col = (cg0 + c) * 16 + r;
                float bb = c ? b1v : b0;
#pragma unroll
                for (int i = 0; i < 4; ++i)
                    H[(rt * 16 + q * 4 + i) * 136 + col] =
                        f2bf(fmaxf(acc1[rt][c][i] + bb, 0.f));
            }
    }
    __syncthreads();

    // ---- stage 6: edge MLP layer 2 + max over K (one 16-row tile = one point)
    {
        short8 wf[2][4];
#pragma unroll
        for (int c = 0; c < 2; ++c)
#pragma unroll
            for (int ks = 0; ks < 4; ++ks)
                wf[c][ks] = *(const short8*)(eW2p + ((cg0 + c) * 16 + r) * NC + ks * 32 + q * 8);
        float eb2v[2] = { eb2[cg0 * 16 + r], eb2[(cg0 + 1) * 16 + r] };
#pragma unroll
        for (int rt = 0; rt < 8; ++rt) {
            short8 af[4];
#pragma unroll
            for (int ks = 0; ks < 4; ++ks)
                af[ks] = *(const short8*)&H[(rt * 16 + r) * 136 + ks * 32 + q * 8];
            floatx4 acc[2] = { {0.f,0.f,0.f,0.f}, {0.f,0.f,0.f,0.f} };
#pragma unroll
            for (int c = 0; c < 2; ++c)
#pragma unroll
                for (int ks = 0; ks < 4; ++ks)
                    acc[c] = MFMA(af[ks], wf[c][ks], acc[c]);
#pragma unroll
            for (int c = 0; c < 2; ++c) {
                float m = fmaxf(fmaxf(acc[c][0], acc[c][1]), fmaxf(acc[c][2], acc[c][3]));
                m = fmaxf(m, __shfl_xor(m, 16));
                m = fmaxf(m, __shfl_xor(m, 32));
                if (q == 0) AGG[rt * NC + (cg0 + c) * 16 + r] = m + eb2v[c];
            }
        }
    }
    __syncthreads();

    // ---- stage 7: assemble update input [agg(128)|self(128)|0(8)] bf16
    if (t < 128) {
        int p = t >> 4, c0 = (t & 15) * 16;
        const float* src = (c0 < 128) ? (AGG + p * NC + c0)
                                      : (s_FSELF + p * NC + (c0 - 128));
#pragma unroll
        for (int g = 0; g < 4; ++g) {
            ushort4v u = { f2bf(src[g * 4 + 0]), f2bf(src[g * 4 + 1]),
                           f2bf(src[g * 4 + 2]), f2bf(src[g * 4 + 3]) };
            *(ushort4v*)&UIN[p * 264 + c0 + g * 4] = u;
        }
    } else if (t < 136) {
        int p = t - 128;
        ushort4v z = {0, 0, 0, 0};
        *(ushort4v*)&UIN[p * 264 + 256] = z;
        *(ushort4v*)&UIN[p * 264 + 260] = z;
    }
    __syncthreads();

    // ---- stage 8: update MLP layer 1 (16x256 -> 128), H2 aliases EI (safe: 2 barriers since last read)
    floatx4 acc3[2] = { {0.f,0.f,0.f,0.f}, {0.f,0.f,0.f,0.f} };
    {
        short8 wf[2][8];
#pragma unroll
        for (int c = 0; c < 2; ++c) {
            int wrow = ((cg0 + c) * 16 + r) * 256;
#pragma unroll
            for (int ks = 0; ks < 8; ++ks)
                wf[c][ks] = *(const short8*)(uW1p + wrow + ks * 32 + q * 8);
        }
        short8 af[8];
#pragma unroll
        for (int ks = 0; ks < 8; ++ks)
            af[ks] = *(const short8*)&UIN[r * 264 + ks * 32 + q * 8];
#pragma unroll
        for (int c = 0; c < 2; ++c)
#pragma unroll
            for (int ks = 0; ks < 8; ++ks)
                acc3[c] = MFMA(af[ks], wf[c][ks], acc3[c]);
    }
    {
#pragma unroll
        for (int c = 0; c < 2; ++c) {
            int col = (cg0 + c) * 16 + r;
            float bv = ub1[col];
#pragma unroll
            for (int i = 0; i < 4; ++i)
                H2[(q * 4 + i) * 136 + col] = f2bf(fmaxf(acc3[c][i] + bv, 0.f));
        }
    }
    __syncthreads();

    // ---- stage 9: update MLP layer 2 + residual, write F_out
    {
        short8 wf[2][4];
#pragma unroll
        for (int c = 0; c < 2; ++c)
#pragma unroll
            for (int ks = 0; ks < 4; ++ks)
                wf[c][ks] = *(const short8*)(uW2p + ((cg0 + c) * 16 + r) * NC + ks * 32 + q * 8);
        short8 af[4];
#pragma unroll
        for (int ks = 0; ks < 4; ++ks)
            af[ks] = *(const short8*)&H2[r * 136 + ks * 32 + q * 8];
        floatx4 acc[2] = { {0.f,0.f,0.f,0.f}, {0.f,0.f,0.f,0.f} };
#pragma unroll
        for (int c = 0; c < 2; ++c)
#pragma unroll
            for (int ks = 0; ks < 4; ++ks)
                acc[c] = MFMA(af[ks], wf[c][ks], acc[c]);
        if (q < 2) {
#pragma unroll
            for (int c = 0; c < 2; ++c) {
                int col = (cg0 + c) * 16 + r;
                float bv = ub2[col];
#pragma unroll
                for (int i = 0; i < 4; ++i) {
                    int p = q * 4 + i;   // 0..7
                    Fout[(size_t)(b * NP + n0 + p) * NC + col] =
                        s_FSELF[p * NC + col] + acc[c][i] + bv;
                }
            }
        }
    }
}

// ---------------------------------------------------------------------------
extern "C" void kernel_launch(void* const* d_in, const int* in_sizes, int n_in,
                              void* d_out, int out_size, void* d_ws, size_t ws_size,
                              hipStream_t stream)
{
    const float* xyz   = (const float*)d_in[0];
    const float* feat  = (const float*)d_in[1];
    const int*   knn   = (const int*)d_in[2];
    const float* offW1 = (const float*)d_in[3];
    const float* offb1 = (const float*)d_in[4];
    const float* offW2 = (const float*)d_in[5];
    const float* offb2 = (const float*)d_in[6];
    const float* eW1   = (const float*)d_in[7];
    const float* eb1   = (const float*)d_in[8];
    const float* eW2   = (const float*)d_in[9];
    const float* eb2   = (const float*)d_in[10];
    const float* uW1   = (const float*)d_in[11];
    const float* ub1   = (const float*)d_in[12];
    const float* uW2   = (const float*)d_in[13];
    const float* ub2   = (const float*)d_in[14];
    float* out = (float*)d_out;

    char* ws = (char*)d_ws;
    float*          F1     = (float*)ws;                          // 16777216 B
    unsigned short* offW1p = (unsigned short*)(ws + 16777216);    // 32768 B
    unsigned short* eW1p   = (unsigned short*)(ws + 16809984);    // 122880 B
    unsigned short* eW2p   = (unsigned short*)(ws + 16932864);    // 98304 B
    unsigned short* uW1p   = (unsigned short*)(ws + 17031168);    // 196608 B
    unsigned short* uW2p   = (unsigned short*)(ws + 17227776);    // 98304 B

    pack_weights_k<<<1072, 256, 0, stream>>>(offW1, eW1, eW2, uW1, uW2,
                                             offW1p, eW1p, eW2p, uW1p, uW2p);

    // ping-pong: F0(in) -> d_out -> F1 -> d_out   (gathers read prev buffer)
    const float* fin[3]  = { feat, out, F1 };
    float*       fout[3] = { out,  F1,  out };
    for (int tt = 0; tt < 3; ++tt) {
        stab_iter_k<<<4096, 256, 0, stream>>>(
            fin[tt], fout[tt], xyz, knn,
            offW1p, offW2, offb1, offb2,
            eW1p + tt * 20480, eW2p + tt * 16384, eb1 + tt * 128, eb2 + tt * 128,
            uW1p + tt * 32768, uW2p + tt * 16384, ub1 + tt * 128, ub2 + tt * 128);
    }
}

// Round 2
// 446.846 us; speedup vs baseline: 1.2693x; 1.2693x over previous
//
#include <hip/hip_runtime.h>
#include <cstddef>

#define NB 4
#define NP 8192
#define NK 16
#define NC 128
#define EIW 168   // EI row stride (bf16): 84 dw % 32 = 20 -> 2-way (free)
#define HW_ 136   // H row stride: 68 dw % 32 = 4 -> 2-way
#define UINW 264  // UIN row stride: 132 dw % 32 = 4 -> 2-way

using short8   = __attribute__((ext_vector_type(8))) short;
using ushort4v = __attribute__((ext_vector_type(4))) unsigned short;
using floatx4  = __attribute__((ext_vector_type(4))) float;

__device__ __forceinline__ unsigned short f2bf(float f) {
    union { float f; unsigned u; } v; v.f = f;
    unsigned r = v.u + 0x7FFFu + ((v.u >> 16) & 1u);   // RNE
    return (unsigned short)(r >> 16);
}

#define MFMA(a, b, c) __builtin_amdgcn_mfma_f32_16x16x32_bf16((a), (b), (c), 0, 0, 0)

// ---------------------------------------------------------------------------
// Weight packing: fp32 -> bf16, edge_W1 reordered to [feat(128)|rel(3)|pad->160]
// ---------------------------------------------------------------------------
__global__ void pack_weights_k(const float* __restrict__ offW1,
                               const float* __restrict__ eW1,
                               const float* __restrict__ eW2,
                               const float* __restrict__ uW1,
                               const float* __restrict__ uW2,
                               unsigned short* __restrict__ offW1p,
                               unsigned short* __restrict__ eW1p,
                               unsigned short* __restrict__ eW2p,
                               unsigned short* __restrict__ uW1p,
                               unsigned short* __restrict__ uW2p)
{
    int i = blockIdx.x * 256 + threadIdx.x;
    if (i < 16384) { offW1p[i] = f2bf(offW1[i]); return; }
    i -= 16384;
    if (i < 61440) {
        int tt = i / 20480, rem = i % 20480;
        int j = rem / 160, k = rem % 160;
        float v = 0.f;
        if (k < 128)      v = eW1[(tt * 128 + j) * 131 + 3 + k];     // feat part
        else if (k < 131) v = eW1[(tt * 128 + j) * 131 + (k - 128)]; // rel part
        eW1p[i] = f2bf(v);
        return;
    }
    i -= 61440;
    if (i < 49152) { eW2p[i] = f2bf(eW2[i]); return; }
    i -= 49152;
    if (i < 98304) { uW1p[i] = f2bf(uW1[i]); return; }
    i -= 98304;
    if (i < 49152) { uW2p[i] = f2bf(uW2[i]); }
}

// ---------------------------------------------------------------------------
// center_k: offset MLP for 16 points/block. Also emits bf16 feature copy Fbf.
// L1 via MFMA (4 waves x 2 col-tiles); L2 (128->3) via MFMA on wave 0 with
// zero-padded B fragment (cols 3..15 = 0).
// ---------------------------------------------------------------------------
__global__ __launch_bounds__(256, 4)
void center_k(const float* __restrict__ Fin, const float* __restrict__ xyz,
              const unsigned short* __restrict__ offW1p,
              const float* __restrict__ offW2, const float* __restrict__ offb1,
              const float* __restrict__ offb2,
              unsigned short* __restrict__ Fbf, float* __restrict__ ctr)
{
    __shared__ __align__(16) unsigned short sA[16 * HW_];
    __shared__ __align__(16) unsigned short sH[16 * HW_];
    const int t = threadIdx.x, wv = t >> 6, ln = t & 63, q = ln >> 4, r = ln & 15;
    const int base = blockIdx.x * 16;     // global row (b*NP+n) base

    {   // load fp32 -> cvt -> LDS A + global Fbf
        int row = t >> 4, c8 = (t & 15) * 8;
        const float* src = Fin + (size_t)(base + row) * NC + c8;
        float4 f0 = *(const float4*)src;
        float4 f1 = *(const float4*)(src + 4);
        short8 u;
        u[0] = f2bf(f0.x); u[1] = f2bf(f0.y); u[2] = f2bf(f0.z); u[3] = f2bf(f0.w);
        u[4] = f2bf(f1.x); u[5] = f2bf(f1.y); u[6] = f2bf(f1.z); u[7] = f2bf(f1.w);
        *(short8*)&sA[row * HW_ + c8] = u;
        *(short8*)(Fbf + (size_t)(base + row) * NC + c8) = u;
    }
    __syncthreads();

    {   // layer 1
        int cg0 = wv << 1;
        short8 wf[2][4];
#pragma unroll
        for (int c = 0; c < 2; ++c)
#pragma unroll
            for (int ks = 0; ks < 4; ++ks)
                wf[c][ks] = *(const short8*)(offW1p + ((cg0 + c) * 16 + r) * NC + ks * 32 + q * 8);
        short8 af[4];
#pragma unroll
        for (int ks = 0; ks < 4; ++ks)
            af[ks] = *(const short8*)&sA[r * HW_ + ks * 32 + q * 8];
        floatx4 acc[2] = { {0.f,0.f,0.f,0.f}, {0.f,0.f,0.f,0.f} };
#pragma unroll
        for (int c = 0; c < 2; ++c)
#pragma unroll
            for (int ks = 0; ks < 4; ++ks)
                acc[c] = MFMA(af[ks], wf[c][ks], acc[c]);
#pragma unroll
        for (int c = 0; c < 2; ++c) {
            int col = (cg0 + c) * 16 + r;
            float bv = offb1[col];
#pragma unroll
            for (int i = 0; i < 4; ++i)
                sH[(q * 4 + i) * HW_ + col] = f2bf(fmaxf(acc[c][i] + bv, 0.f));
        }
    }
    __syncthreads();

    if (wv == 0) {   // layer 2 (out=3, zero-padded to 16 cols)
        short8 wf[4];
#pragma unroll
        for (int ks = 0; ks < 4; ++ks) {
            short8 u = {0,0,0,0,0,0,0,0};
            if (r < 3) {
                const float* w = offW2 + r * NC + ks * 32 + q * 8;
                float4 f0 = *(const float4*)w;
                float4 f1 = *(const float4*)(w + 4);
                u[0] = f2bf(f0.x); u[1] = f2bf(f0.y); u[2] = f2bf(f0.z); u[3] = f2bf(f0.w);
                u[4] = f2bf(f1.x); u[5] = f2bf(f1.y); u[6] = f2bf(f1.z); u[7] = f2bf(f1.w);
            }
            wf[ks] = u;
        }
        short8 af[4];
#pragma unroll
        for (int ks = 0; ks < 4; ++ks)
            af[ks] = *(const short8*)&sH[r * HW_ + ks * 32 + q * 8];
        floatx4 acc = {0.f, 0.f, 0.f, 0.f};
#pragma unroll
        for (int ks = 0; ks < 4; ++ks)
            acc = MFMA(af[ks], wf[ks], acc);
        if (r < 3) {
#pragma unroll
            for (int i = 0; i < 4; ++i) {
                int p = q * 4 + i;
                ctr[(size_t)(base + p) * 3 + r] =
                    xyz[(size_t)(base + p) * 3 + r] + acc[i] + offb2[r];
            }
        }
    }
}

// ---------------------------------------------------------------------------
// Fused iteration: gather(bf16) -> edge MLP -> max(K) -> update MLP -> residual
// Block = 256 thr (4 waves), 8 points; edge rows processed in 2 halves of 64.
// LDS 30304 B -> 4 blocks/CU (VGPR-capped at 128 via launch_bounds).
// ---------------------------------------------------------------------------
__global__ __launch_bounds__(256, 4)
void stab_iter_k(const float* __restrict__ Fin, float* __restrict__ Fout,
                 const unsigned short* __restrict__ Fbf,
                 const float* __restrict__ xyz, const int* __restrict__ knn,
                 const float* __restrict__ ctr,
                 const unsigned short* __restrict__ eW1p,
                 const unsigned short* __restrict__ eW2p,
                 const float* __restrict__ eb1, const float* __restrict__ eb2,
                 const unsigned short* __restrict__ uW1p,
                 const unsigned short* __restrict__ uW2p,
                 const float* __restrict__ ub1, const float* __restrict__ ub2)
{
    __shared__ __align__(16) unsigned short s_EI[64 * EIW];   // 21504 B
    __shared__ __align__(16) float s_AGG[8 * NC];             // 4096
    __shared__ __align__(16) float s_FSELF[8 * NC];           // 4096
    __shared__ int   s_KNN[128];                              // 512
    __shared__ float s_CTR[8][3];                             // 96

    unsigned short* H   = s_EI;                                    // 64 x 136 (alias)
    unsigned short* UIN = s_EI;                                    // 8 x 264 (alias)
    unsigned short* H2  = (unsigned short*)((char*)s_EI + 16384);  // 16 x 136 (alias)

    // XCD swizzle: batch b -> XCDs {2b, 2b+1} (L2 locality for gathers)
    const int xcd  = blockIdx.x & 7;
    const int slot = blockIdx.x >> 3;
    const int b    = xcd >> 1;
    const int n0   = ((slot << 1) | (xcd & 1)) << 3;
    const int t = threadIdx.x, wv = t >> 6, ln = t & 63;
    const int q = ln >> 4, r = ln & 15, cg0 = wv << 1;

    // ---- stage 1: self features (fp32), knn, centers
    {
        int row = t >> 5, c4 = (t & 31) << 2;
        float4 f = *(const float4*)(Fin + (size_t)(b * NP + n0 + row) * NC + c4);
        *(float4*)&s_FSELF[row * NC + c4] = f;
        if (t < 128)
            s_KNN[t] = knn[(size_t)(b * NP + n0 + (t >> 4)) * NK + (t & 15)];
        if (t < 24) {
            int p = t / 3, o = t % 3;
            s_CTR[p][o] = ctr[(size_t)(b * NP + n0 + p) * 3 + o];
        }
    }
    // edge L1 weight frags persist across both halves
    short8 wf1[2][5];
#pragma unroll
    for (int c = 0; c < 2; ++c)
#pragma unroll
        for (int ks = 0; ks < 5; ++ks)
            wf1[c][ks] = *(const short8*)(eW1p + ((cg0 + c) * 16 + r) * 160 + ks * 32 + q * 8);
    float eb1v[2] = { eb1[cg0 * 16 + r], eb1[(cg0 + 1) * 16 + r] };
    float eb2v[2] = { eb2[cg0 * 16 + r], eb2[(cg0 + 1) * 16 + r] };
    __syncthreads();

#pragma unroll
    for (int h = 0; h < 2; ++h) {
        // ---- gather 64 edge rows (bf16, 256 B/row) + rel-pos
        {
            int rr = t >> 4, c8 = (t & 15) * 8;
#pragma unroll
            for (int pass = 0; pass < 4; ++pass) {
                int row64 = pass * 16 + rr;
                int nb = s_KNN[h * 64 + row64];
                short8 u = *(const short8*)(Fbf + (size_t)(b * NP + nb) * NC + c8);
                *(short8*)&s_EI[row64 * EIW + c8] = u;
            }
        }
        if (t < 64) {
            int row64 = t, p = h * 4 + (t >> 4);
            int nb = s_KNN[h * 64 + row64];
            const float* xp = xyz + (size_t)(b * NP + nb) * 3;
            ushort4v rv = { f2bf(xp[0] - s_CTR[p][0]), f2bf(xp[1] - s_CTR[p][1]),
                            f2bf(xp[2] - s_CTR[p][2]), 0 };
            *(ushort4v*)&s_EI[row64 * EIW + 128] = rv;
            ushort4v z = {0, 0, 0, 0};
#pragma unroll
            for (int g = 1; g < 8; ++g)
                *(ushort4v*)&s_EI[row64 * EIW + 128 + g * 4] = z;
        }
        __syncthreads();

        // ---- edge L1 (4 row-tiles x 2 col-tiles x 5 K-steps)
        floatx4 acc1[4][2];
#pragma unroll
        for (int rt = 0; rt < 4; ++rt) {
            acc1[rt][0] = (floatx4){0.f,0.f,0.f,0.f};
            acc1[rt][1] = (floatx4){0.f,0.f,0.f,0.f};
            short8 af[5];
#pragma unroll
            for (int ks = 0; ks < 5; ++ks)
                af[ks] = *(const short8*)&s_EI[(rt * 16 + r) * EIW + ks * 32 + q * 8];
#pragma unroll
            for (int c = 0; c < 2; ++c)
#pragma unroll
                for (int ks = 0; ks < 5; ++ks)
                    acc1[rt][c] = MFMA(af[ks], wf1[c][ks], acc1[rt][c]);
        }
        __syncthreads();   // EI consumed; H aliases it

        // ---- bias+relu -> H (bf16)
#pragma unroll
        for (int rt = 0; rt < 4; ++rt)
#pragma unroll
            for (int c = 0; c < 2; ++c) {
                int col = (cg0 + c) * 16 + r;
#pragma unroll
                for (int i = 0; i < 4; ++i)
                    H[(rt * 16 + q * 4 + i) * HW_ + col] =
                        f2bf(fmaxf(acc1[rt][c][i] + eb1v[c], 0.f));
            }
        __syncthreads();

        // ---- edge L2 + max over K (16-row tile = one point)
        {
            short8 wf2[2][4];
#pragma unroll
            for (int c = 0; c < 2; ++c)
#pragma unroll
                for (int ks = 0; ks < 4; ++ks)
                    wf2[c][ks] = *(const short8*)(eW2p + ((cg0 + c) * 16 + r) * NC + ks * 32 + q * 8);
#pragma unroll
            for (int rt = 0; rt < 4; ++rt) {
                short8 af[4];
#pragma unroll
                for (int ks = 0; ks < 4; ++ks)
                    af[ks] = *(const short8*)&H[(rt * 16 + r) * HW_ + ks * 32 + q * 8];
                floatx4 acc[2] = { {0.f,0.f,0.f,0.f}, {0.f,0.f,0.f,0.f} };
#pragma unroll
                for (int c = 0; c < 2; ++c)
#pragma unroll
                    for (int ks = 0; ks < 4; ++ks)
                        acc[c] = MFMA(af[ks], wf2[c][ks], acc[c]);
#pragma unroll
                for (int c = 0; c < 2; ++c) {
                    float m = fmaxf(fmaxf(acc[c][0], acc[c][1]), fmaxf(acc[c][2], acc[c][3]));
                    m = fmaxf(m, __shfl_xor(m, 16));
                    m = fmaxf(m, __shfl_xor(m, 32));
                    if (q == 0)
                        s_AGG[(h * 4 + rt) * NC + (cg0 + c) * 16 + r] = m + eb2v[c];
                }
            }
        }
        __syncthreads();   // H consumed; next gather may overwrite EI
    }

    // ---- UIN assembly [agg(128) | self(128)] bf16, rows 0..7
    if (t < 128) {
        int p = t >> 4, c0 = (t & 15) * 16;
        const float* src = (c0 < 128) ? (s_AGG + p * NC + c0)
                                      : (s_FSELF + p * NC + (c0 - 128));
#pragma unroll
        for (int g = 0; g < 4; ++g) {
            ushort4v u = { f2bf(src[g * 4 + 0]), f2bf(src[g * 4 + 1]),
                           f2bf(src[g * 4 + 2]), f2bf(src[g * 4 + 3]) };
            *(ushort4v*)&UIN[p * UINW + c0 + g * 4] = u;
        }
    }
    __syncthreads();

    // ---- update L1 (K=256) -> H2
    {
        floatx4 acc3[2] = { {0.f,0.f,0.f,0.f}, {0.f,0.f,0.f,0.f} };
        short8 wf[2][8];
#pragma unroll
        for (int c = 0; c < 2; ++c)
#pragma unroll
            for (int ks = 0; ks < 8; ++ks)
                wf[c][ks] = *(const short8*)(uW1p + ((cg0 + c) * 16 + r) * 256 + ks * 32 + q * 8);
        short8 af[8];
#pragma unroll
        for (int ks = 0; ks < 8; ++ks)
            af[ks] = *(const short8*)&UIN[r * UINW + ks * 32 + q * 8];
#pragma unroll
        for (int c = 0; c < 2; ++c)
#pragma unroll
            for (int ks = 0; ks < 8; ++ks)
                acc3[c] = MFMA(af[ks], wf[c][ks], acc3[c]);
#pragma unroll
        for (int c = 0; c < 2; ++c) {
            int col = (cg0 + c) * 16 + r;
            float bv = ub1[col];
#pragma unroll
            for (int i = 0; i < 4; ++i)
                H2[(q * 4 + i) * HW_ + col] = f2bf(fmaxf(acc3[c][i] + bv, 0.f));
        }
    }
    __syncthreads();

    // ---- update L2 + residual -> Fout
    {
        short8 wf[2][4];
#pragma unroll
        for (int c = 0; c < 2; ++c)
#pragma unroll
            for (int ks = 0; ks < 4; ++ks)
                wf[c][ks] = *(const short8*)(uW2p + ((cg0 + c) * 16 + r) * NC + ks * 32 + q * 8);
        short8 af[4];
#pragma unroll
        for (int ks = 0; ks < 4; ++ks)
            af[ks] = *(const short8*)&H2[r * HW_ + ks * 32 + q * 8];
        floatx4 acc[2] = { {0.f,0.f,0.f,0.f}, {0.f,0.f,0.f,0.f} };
#pragma unroll
        for (int c = 0; c < 2; ++c)
#pragma unroll
            for (int ks = 0; ks < 4; ++ks)
                acc[c] = MFMA(af[ks], wf[c][ks], acc[c]);
        if (q < 2) {
#pragma unroll
            for (int c = 0; c < 2; ++c) {
                int col = (cg0 + c) * 16 + r;
                float bv = ub2[col];
#pragma unroll
                for (int i = 0; i < 4; ++i) {
                    int p = q * 4 + i;   // 0..7
                    Fout[(size_t)(b * NP + n0 + p) * NC + col] =
                        s_FSELF[p * NC + col] + acc[c][i] + bv;
                }
            }
        }
    }
}

// ---------------------------------------------------------------------------
extern "C" void kernel_launch(void* const* d_in, const int* in_sizes, int n_in,
                              void* d_out, int out_size, void* d_ws, size_t ws_size,
                              hipStream_t stream)
{
    const float* xyz   = (const float*)d_in[0];
    const float* feat  = (const float*)d_in[1];
    const int*   knn   = (const int*)d_in[2];
    const float* offW1 = (const float*)d_in[3];
    const float* offb1 = (const float*)d_in[4];
    const float* offW2 = (const float*)d_in[5];
    const float* offb2 = (const float*)d_in[6];
    const float* eW1   = (const float*)d_in[7];
    const float* eb1   = (const float*)d_in[8];
    const float* eW2   = (const float*)d_in[9];
    const float* eb2   = (const float*)d_in[10];
    const float* uW1   = (const float*)d_in[11];
    const float* ub1   = (const float*)d_in[12];
    const float* uW2   = (const float*)d_in[13];
    const float* ub2   = (const float*)d_in[14];
    float* out = (float*)d_out;

    char* ws = (char*)d_ws;
    unsigned short* Fbf    = (unsigned short*)ws;                 // 8388608 B
    float*          ctrb   = (float*)(ws + 8388608);              // 393216 B
    unsigned short* offW1p = (unsigned short*)(ws + 8781824);     // 32768 B
    unsigned short* eW1p   = (unsigned short*)(ws + 8814592);     // 122880 B
    unsigned short* eW2p   = (unsigned short*)(ws + 8937472);     // 98304 B
    unsigned short* uW1p   = (unsigned short*)(ws + 9035776);     // 196608 B
    unsigned short* uW2p   = (unsigned short*)(ws + 9232384);     // 98304 B

    pack_weights_k<<<1072, 256, 0, stream>>>(offW1, eW1, eW2, uW1, uW2,
                                             offW1p, eW1p, eW2p, uW1p, uW2p);

    // fp32 features: feat -> d_out (t=0), then in place in d_out (only the
    // owning block reads/writes its rows; gathers use the bf16 copy Fbf,
    // which center_k regenerates before each fused launch).
    const float* fin[3]  = { feat, out, out };
    for (int tt = 0; tt < 3; ++tt) {
        center_k<<<2048, 256, 0, stream>>>(fin[tt], xyz, offW1p, offW2,
                                           offb1, offb2, Fbf, ctrb);
        stab_iter_k<<<4096, 256, 0, stream>>>(
            fin[tt], out, Fbf, xyz, knn, ctrb,
            eW1p + tt * 20480, eW2p + tt * 16384, eb1 + tt * 128, eb2 + tt * 128,
            uW1p + tt * 32768, uW2p + tt * 16384, ub1 + tt * 128, ub2 + tt * 128);
    }
}